// Round 3
// baseline (21.598 us; speedup 1.0000x reference)
//
#include <hip/hip_runtime.h>

// Problem constants: B=16,T=4 (64 slices), N=512 nodes, H=W=128, P=4096 points
// nodes row = 132 floats (33 float4); we need float4s 0..10 (coeffs 0..43) + 32 (h,w,?,valid)
#define N_NODES   512
#define HH        128
#define WW        128
#define ROW_F4    33
#define NJ        12                     // staged float4s per row
#define LDS_BYTES (NJ * N_NODES * 16)    // 98304 B (96 KB), layout [j][row]

typedef const __attribute__((address_space(1))) void g_void;
typedef __attribute__((address_space(3))) void l_void;

// Accumulate coefficient M (0..41) * its delta into the right head
#define ACC(M, V) do {                                              \
    if constexpr ((M) < 6)       depth      += (V) * dlt[(M)];      \
    else if constexpr ((M) < 24) img[((M)-6)%3]  += (V) * dlt[((M)-6)/3];  \
    else if constexpr ((M) < 42) nrm[((M)-24)%3] += (V) * dlt[((M)-24)/3]; \
} while (0)

#define DOJ(J) {                                                    \
    float4 q = ldsT[(J) * N_NODES + sc];                            \
    ACC(4*(J)+0, q.x); ACC(4*(J)+1, q.y);                           \
    ACC(4*(J)+2, q.z); ACC(4*(J)+3, q.w);                           \
}

__global__ __launch_bounds__(1024, 1) void qtr_decoder_kernel(
    const float* __restrict__ nodes,   // (64, 512, 132)
    const int*   __restrict__ seg_ids, // (64, 128, 128)
    const int*   __restrict__ sp_inds, // (64, 4096, 2)
    float*       __restrict__ out)     // (64, 4096, 7)
{
    extern __shared__ float4 ldsT[];   // [12][512] float4, linear-fill friendly

    const int tid = threadIdx.x;
    const int blk = blockIdx.x;        // 0..255
    const int bt  = blk >> 2;          // 0..63
    const int p   = (blk << 10) + tid; // global point index

    // ---- Prefetch point data early (overlaps staging latency)
    int2 si = ((const int2*)sp_inds)[p];
    int seg = seg_ids[(bt << 14) + si.x * WW + si.y];

    // ---- Stage node slice via async global->LDS, 6 float4 per thread.
    // LDS linear index i = j*512 + r  (j = i>>9, r = i&511): per-wave dest is
    // uniform base + lane*16; global source is per-lane (allowed).
    const float4* nb = (const float4*)nodes + (size_t)bt * N_NODES * ROW_F4;
#pragma unroll
    for (int it = 0; it < 6; ++it) {
        int i = tid + (it << 10);
        int r = i & (N_NODES - 1);
        int j = i >> 9;
        int srcj = (j < 11) ? j : 32;
        __builtin_amdgcn_global_load_lds(
            (g_void*)(nb + r * ROW_F4 + srcj),
            (l_void*)(ldsT + i),
            16, 0, 0);
    }
    __syncthreads();

    // ---- Decode one point
    float vseg = (seg >= 0 && seg < N_NODES) ? 1.0f : 0.0f;
    int sc = min(max(seg, 0), N_NODES - 1);

    float4 tail = ldsT[11 * N_NODES + sc];          // h, w, (unused), valid
    float vdec = ((tail.w > 0.0f) ? 1.0f : 0.0f) * vseg;

    const float invScale = 2.0f / (HH - 1);
    float dH = (-1.0f + (float)si.x * invScale) - tail.x;
    float dW = (-1.0f + (float)si.y * invScale) - tail.y;
    float dlt[6] = { 1.0f, dH, dW, dH * dH, dH * dW, dW * dW };

    float depth = 0.0f;
    float img[3] = {0.0f, 0.0f, 0.0f};
    float nrm[3] = {0.0f, 0.0f, 0.0f};

    DOJ(0) DOJ(1) DOJ(2) DOJ(3) DOJ(4) DOJ(5)
    DOJ(6) DOJ(7) DOJ(8) DOJ(9) DOJ(10)

    depth *= vdec;
    depth = fminf(depth, -0.1f);

    float ss = 0.0f;
#pragma unroll
    for (int ch = 0; ch < 3; ++ch) {
        img[ch] *= vdec;
        img[ch] = fminf(fmaxf(img[ch], -100.0f), 100.0f);
        nrm[ch] *= vdec;
        ss += nrm[ch] * nrm[ch];
    }
    float inv = 1.0f / sqrtf(fmaxf(ss, 1e-12f));

    // ---- Coalesced output: transpose through LDS (reuse node buffer)
    __syncthreads();                    // everyone done reading node LDS
    float* ldsF = (float*)ldsT;         // 1024*7*4 = 28 KB needed
    float* w = ldsF + tid * 7;          // stride 7 (odd) -> conflict-free
    w[0] = depth;
    w[1] = img[0]; w[2] = img[1]; w[3] = img[2];
    w[4] = nrm[0] * inv; w[5] = nrm[1] * inv; w[6] = nrm[2] * inv;
    __syncthreads();

    // 1024 points * 7 floats = 7168 floats = 1792 float4, contiguous
    float4* out4 = (float4*)(out + (size_t)blk * 1024 * 7);
    const float4* ldsF4 = (const float4*)ldsF;
    out4[tid] = ldsF4[tid];
    if (tid < 768) out4[tid + 1024] = ldsF4[tid + 1024];
}

extern "C" void kernel_launch(void* const* d_in, const int* in_sizes, int n_in,
                              void* d_out, int out_size, void* d_ws, size_t ws_size,
                              hipStream_t stream) {
    const float* nodes = (const float*)d_in[0];
    const int*   seg   = (const int*)d_in[1];
    const int*   sp    = (const int*)d_in[2];
    float* out = (float*)d_out;

    qtr_decoder_kernel<<<256, 1024, LDS_BYTES, stream>>>(nodes, seg, sp, out);
}

// Round 4
// 18.748 us; speedup vs baseline: 1.1520x; 1.1520x over previous
//
#include <hip/hip_runtime.h>

// B=16,T=4 (64 slices), N=512 nodes, H=W=128, P=4096 points/slice
// nodes row = 132 floats (33 float4); needed: float4 j=0..10 (coeffs 0..43) + j=32 (h,w,?,valid)
#define N_NODES   512
#define HH        128
#define WW        128
#define ROW_F4    33
#define SLOTS     16                         // 12 meaningful + 4 pad (XOR-closed)
#define LDS_BYTES (N_NODES * SLOTS * 16)     // 131072 B

typedef const __attribute__((address_space(1))) void g_void;
typedef __attribute__((address_space(3))) void l_void;

// Accumulate coefficient M (0..41) * its delta into the right head
#define ACC(M, V) do {                                              \
    if constexpr ((M) < 6)       depth      += (V) * dlt[(M)];      \
    else if constexpr ((M) < 24) img[((M)-6)%3]  += (V) * dlt[((M)-6)/3];  \
    else if constexpr ((M) < 42) nrm[((M)-24)%3] += (V) * dlt[((M)-24)/3]; \
} while (0)

// Read row sc, logical float4 jd=J from swizzled LDS slot (J ^ (sc&7))
#define DOJ(J) {                                                    \
    float4 q = lds4[rowbase + ((J) ^ scx)];                         \
    ACC(4*(J)+0, q.x); ACC(4*(J)+1, q.y);                           \
    ACC(4*(J)+2, q.z); ACC(4*(J)+3, q.w);                           \
}

__global__ __launch_bounds__(1024, 1) void qtr_decoder_kernel(
    const float* __restrict__ nodes,   // (64, 512, 132)
    const int*   __restrict__ seg_ids, // (64, 128, 128)
    const int*   __restrict__ sp_inds, // (64, 4096, 2)
    float*       __restrict__ out)     // (64, 4096, 7)
{
    extern __shared__ float4 lds4[];   // [512][16], slot js holds jd = js ^ (r&7)

    const int tid = threadIdx.x;
    const int blk = blockIdx.x;        // 0..255
    const int bt  = blk >> 2;          // 0..63
    const int p   = (blk << 10) + tid; // global point index

    // ---- Prefetch point data early (overlaps staging latency)
    int2 si = ((const int2*)sp_inds)[p];
    int seg = seg_ids[(bt << 14) + si.x * WW + si.y];

    // ---- Stage node slice: linear LDS dest, row-local XOR-permuted source.
    // i = r*16 + js; data at slot js of row r is logical jd = js ^ (r&7).
    // Source float4: jd<11 -> jd; jd==11 -> 32 (tail); jd 12..15 -> jd (pad, never read).
    const float4* nb = (const float4*)nodes + (size_t)bt * N_NODES * ROW_F4;
#pragma unroll
    for (int it = 0; it < 8; ++it) {
        int i  = tid + (it << 10);     // 0..8191
        int r  = i >> 4;
        int js = i & 15;
        int jd = js ^ (r & 7);
        int srcj = (jd == 11) ? 32 : jd;
        __builtin_amdgcn_global_load_lds(
            (g_void*)(nb + r * ROW_F4 + srcj),
            (l_void*)(lds4 + i),
            16, 0, 0);
    }
    __syncthreads();

    // ---- Decode one point
    float vseg = (seg >= 0 && seg < N_NODES) ? 1.0f : 0.0f;
    int sc  = min(max(seg, 0), N_NODES - 1);
    int scx = sc & 7;
    int rowbase = sc << 4;

    float4 tail = lds4[rowbase + (11 ^ scx)];       // h, w, (unused), valid
    float vdec = ((tail.w > 0.0f) ? 1.0f : 0.0f) * vseg;

    const float invScale = 2.0f / (HH - 1);
    float dH = (-1.0f + (float)si.x * invScale) - tail.x;
    float dW = (-1.0f + (float)si.y * invScale) - tail.y;
    float dlt[6] = { 1.0f, dH, dW, dH * dH, dH * dW, dW * dW };

    float depth = 0.0f;
    float img[3] = {0.0f, 0.0f, 0.0f};
    float nrm[3] = {0.0f, 0.0f, 0.0f};

    DOJ(0) DOJ(1) DOJ(2) DOJ(3) DOJ(4) DOJ(5)
    DOJ(6) DOJ(7) DOJ(8) DOJ(9) DOJ(10)

    depth *= vdec;
    depth = fminf(depth, -0.1f);

    float ss = 0.0f;
#pragma unroll
    for (int ch = 0; ch < 3; ++ch) {
        img[ch] *= vdec;
        img[ch] = fminf(fmaxf(img[ch], -100.0f), 100.0f);
        nrm[ch] *= vdec;
        ss += nrm[ch] * nrm[ch];
    }
    float inv = 1.0f / sqrtf(fmaxf(ss, 1e-12f));

    // ---- Coalesced output: transpose through LDS (reuse node buffer)
    __syncthreads();                    // all node-data reads complete
    float* ldsF = (float*)lds4;         // need 1024*7*4 = 28 KB
    float* w = ldsF + tid * 7;          // stride 7 (odd) -> 2 lanes/bank, free
    w[0] = depth;
    w[1] = img[0]; w[2] = img[1]; w[3] = img[2];
    w[4] = nrm[0] * inv; w[5] = nrm[1] * inv; w[6] = nrm[2] * inv;
    __syncthreads();

    // 1024 points * 7 floats = 1792 float4, fully coalesced
    float4* out4 = (float4*)(out + (size_t)blk * 1024 * 7);
    const float4* ldsF4 = (const float4*)ldsF;
    out4[tid] = ldsF4[tid];
    if (tid < 768) out4[tid + 1024] = ldsF4[tid + 1024];
}

extern "C" void kernel_launch(void* const* d_in, const int* in_sizes, int n_in,
                              void* d_out, int out_size, void* d_ws, size_t ws_size,
                              hipStream_t stream) {
    const float* nodes = (const float*)d_in[0];
    const int*   seg   = (const int*)d_in[1];
    const int*   sp    = (const int*)d_in[2];
    float* out = (float*)d_out;

    qtr_decoder_kernel<<<256, 1024, LDS_BYTES, stream>>>(nodes, seg, sp, out);
}

// Round 5
// 13.026 us; speedup vs baseline: 1.6581x; 1.4393x over previous
//
#include <hip/hip_runtime.h>

// B=16,T=4 -> 64 (b,t) slices; N=512 nodes; H=W=128; P=4096 points/slice
// node row = 132 floats (528 B); coeffs c0..41 = floats 0..41; tail = floats 128..131
#define N_NODES 512
#define WW      128
#define ROW_F   132

__global__ __launch_bounds__(256) void qtr_coop_kernel(
    const float* __restrict__ nodes,   // (64, 512, 132)
    const int*   __restrict__ seg_ids, // (64, 128, 128)
    const int*   __restrict__ sp_inds, // (64, 4096, 2)
    float*       __restrict__ out)     // (64, 4096, 7)
{
    // XCD swizzle: blocks with same (b,t) land on one XCD (blockIdx%8 = XCD id,
    // 4096 blocks, 64 blocks per bt, 512 blocks per XCD -> 8 bts per XCD)
    const int wk  = ((blockIdx.x & 7) << 9) + (blockIdx.x >> 3);  // logical block
    const int tid = threadIdx.x;
    const int p   = (wk << 6) + (tid >> 2);   // point index, 64 pts/block
    const int g   = tid & 3;                  // role within 4-lane group
    const int lane = tid & 63;
    const int bt  = p >> 12;

    // per-point scalars (all 4 lanes load same addr -> merged in TA)
    int2 si = ((const int2*)sp_inds)[p];
    int seg = seg_ids[(bt << 14) + si.x * WW + si.y];
    float vseg = (seg >= 0 && seg < N_NODES) ? 1.0f : 0.0f;
    int sc = min(max(seg, 0), N_NODES - 1);

    // cooperative gather: group reads 64 B contiguous per instr
    const float4* row = (const float4*)(nodes + (size_t)(bt * N_NODES + sc) * ROW_F);
    float4 q0 = row[g];                        // coeffs 4g..4g+3
    float4 q1 = row[4 + g];                    // coeffs 16+4g..19+4g
    float4 q2 = row[(g == 3) ? 32 : (8 + g)];  // coeffs 32+4g.. / tail on lane3

    // broadcast tail (h, w, valid) from role-3 lane of the group
    int srcl = lane | 3;
    float th = __shfl(q2.x, srcl);
    float tw = __shfl(q2.y, srcl);
    float tv = __shfl(q2.w, srcl);

    float vdec = ((tv > 0.0f) ? 1.0f : 0.0f) * vseg;
    const float invScale = 2.0f / 127.0f;
    float dH = (-1.0f + (float)si.x * invScale) - th;
    float dW = (-1.0f + (float)si.y * invScale) - tw;
    float dHH = dH * dH, dHW = dH * dW, dWW = dW * dW;

    float depth = 0.f, i0 = 0.f, i1 = 0.f, i2 = 0.f, n0 = 0.f, n1 = 0.f, n2 = 0.f;

    // partial dots; coefficient->(head,delta) mapping is compile-time per case
    switch (g) {
    case 0:  // m = 0..3, 16..19, 32..35
        depth += q0.x;        depth += q0.y * dH;  depth += q0.z * dW;  depth += q0.w * dHH;
        i1 += q1.x * dHH;     i2 += q1.y * dHH;    i0 += q1.z * dHW;    i1 += q1.w * dHW;
        n2 += q2.x * dW;      n0 += q2.y * dHH;    n1 += q2.z * dHH;    n2 += q2.w * dHH;
        break;
    case 1:  // m = 4..7, 20..23, 36..39
        depth += q0.x * dHW;  depth += q0.y * dWW; i0 += q0.z;          i1 += q0.w;
        i2 += q1.x * dHW;     i0 += q1.y * dWW;    i1 += q1.z * dWW;    i2 += q1.w * dWW;
        n0 += q2.x * dHW;     n1 += q2.y * dHW;    n2 += q2.z * dHW;    n0 += q2.w * dWW;
        break;
    case 2:  // m = 8..11, 24..27, 40..41
        i2 += q0.x;           i0 += q0.y * dH;     i1 += q0.z * dH;     i2 += q0.w * dH;
        n0 += q1.x;           n1 += q1.y;          n2 += q1.z;          n0 += q1.w * dH;
        n1 += q2.x * dWW;     n2 += q2.y * dWW;
        break;
    default: // m = 12..15, 28..31 (q2 = tail, no coeffs)
        i0 += q0.x * dW;      i1 += q0.y * dW;     i2 += q0.z * dW;     i0 += q0.w * dHH;
        n1 += q1.x * dH;      n2 += q1.y * dH;     n0 += q1.z * dW;     n1 += q1.w * dW;
        break;
    }

    // butterfly-sum the 7 outputs within each 4-lane group
#pragma unroll
    for (int mask = 1; mask <= 2; mask <<= 1) {
        depth += __shfl_xor(depth, mask);
        i0 += __shfl_xor(i0, mask);  i1 += __shfl_xor(i1, mask);  i2 += __shfl_xor(i2, mask);
        n0 += __shfl_xor(n0, mask);  n1 += __shfl_xor(n1, mask);  n2 += __shfl_xor(n2, mask);
    }

    // heads (computed redundantly on all 4 lanes)
    depth *= vdec;
    depth = fminf(depth, -0.1f);
    i0 = fminf(fmaxf(i0 * vdec, -100.f), 100.f);
    i1 = fminf(fmaxf(i1 * vdec, -100.f), 100.f);
    i2 = fminf(fmaxf(i2 * vdec, -100.f), 100.f);
    n0 *= vdec; n1 *= vdec; n2 *= vdec;
    float ss = n0 * n0 + n1 * n1 + n2 * n2;
    float inv = 1.0f / sqrtf(fmaxf(ss, 1e-12f));
    n0 *= inv; n1 *= inv; n2 *= inv;

    // distributed store: lane g writes floats g and 4+g of [d,i0,i1,i2,n0,n1,n2]
    float* o = out + (size_t)p * 7;
    float va = (g == 0) ? depth : (g == 1) ? i0 : (g == 2) ? i1 : i2;
    o[g] = va;
    if (g < 3) {
        float vb = (g == 0) ? n0 : (g == 1) ? n1 : n2;
        o[4 + g] = vb;
    }
}

extern "C" void kernel_launch(void* const* d_in, const int* in_sizes, int n_in,
                              void* d_out, int out_size, void* d_ws, size_t ws_size,
                              hipStream_t stream) {
    const float* nodes = (const float*)d_in[0];
    const int*   seg   = (const int*)d_in[1];
    const int*   sp    = (const int*)d_in[2];
    float* out = (float*)d_out;

    // 262144 points x 4 lanes = 1,048,576 threads = 4096 blocks x 256
    qtr_coop_kernel<<<4096, 256, 0, stream>>>(nodes, seg, sp, out);
}

// Round 7
// 12.347 us; speedup vs baseline: 1.7493x; 1.0550x over previous
//
#include <hip/hip_runtime.h>

// B=16,T=4 -> 64 (b,t) slices; N=512 nodes; H=W=128; P=4096 points/slice
// node row = 132 floats (528 B); coeffs c0..41 = floats 0..41; tail = floats 128..131
#define N_NODES 512
#define WW      128
#define ROW_F   132

typedef float f32x2 __attribute__((ext_vector_type(2)));

__global__ __launch_bounds__(256) void qtr_coop_kernel(
    const float* __restrict__ nodes,   // (64, 512, 132)
    const int*   __restrict__ seg_ids, // (64, 128, 128)
    const int*   __restrict__ sp_inds, // (64, 4096, 2)
    float*       __restrict__ out)     // (64, 4096, 7)
{
    // XCD swizzle: blockIdx%8 = XCD id; 64 blocks per (b,t), 512 blocks/XCD
    const int wk  = ((blockIdx.x & 7) << 9) + (blockIdx.x >> 3);  // logical block
    const int tid = threadIdx.x;
    const int p   = (wk << 6) + (tid >> 2);   // point index, 64 pts/block
    const int g   = tid & 3;                  // role within 4-lane group
    const int lane = tid & 63;
    const int bt  = p >> 12;

    // per-point scalars (4 lanes same addr -> merged request)
    int2 si = ((const int2*)sp_inds)[p];
    int seg = seg_ids[(bt << 14) + si.x * WW + si.y];
    float vseg = (seg >= 0 && seg < N_NODES) ? 1.0f : 0.0f;
    int sc = min(max(seg, 0), N_NODES - 1);

    // cooperative gather: group reads 64 B contiguous per instr
    const float4* row = (const float4*)(nodes + (size_t)(bt * N_NODES + sc) * ROW_F);
    float4 q0 = row[g];                        // coeffs 4g..4g+3
    float4 q1 = row[4 + g];                    // coeffs 16+4g..19+4g
    float4 q2 = row[(g == 3) ? 32 : (8 + g)];  // coeffs 32+4g.. / tail on lane3

    // broadcast tail (h, w, valid) from role-3 lane of the group
    int srcl = lane | 3;
    float th = __shfl(q2.x, srcl);
    float tw = __shfl(q2.y, srcl);
    float tv = __shfl(q2.w, srcl);

    float vdec = ((tv > 0.0f) ? 1.0f : 0.0f) * vseg;
    const float invScale = 2.0f / 127.0f;
    float dH = (-1.0f + (float)si.x * invScale) - th;
    float dW = (-1.0f + (float)si.y * invScale) - tw;
    float dHH = dH * dH, dHW = dH * dW, dWW = dW * dW;

    float depth = 0.f, i0 = 0.f, i1 = 0.f, i2 = 0.f, n0 = 0.f, n1 = 0.f, n2 = 0.f;

    // partial dots; coefficient->(head,delta) mapping is compile-time per case
    switch (g) {
    case 0:  // m = 0..3, 16..19, 32..35
        depth += q0.x;        depth += q0.y * dH;  depth += q0.z * dW;  depth += q0.w * dHH;
        i1 += q1.x * dHH;     i2 += q1.y * dHH;    i0 += q1.z * dHW;    i1 += q1.w * dHW;
        n2 += q2.x * dW;      n0 += q2.y * dHH;    n1 += q2.z * dHH;    n2 += q2.w * dHH;
        break;
    case 1:  // m = 4..7, 20..23, 36..39
        depth += q0.x * dHW;  depth += q0.y * dWW; i0 += q0.z;          i1 += q0.w;
        i2 += q1.x * dHW;     i0 += q1.y * dWW;    i1 += q1.z * dWW;    i2 += q1.w * dWW;
        n0 += q2.x * dHW;     n1 += q2.y * dHW;    n2 += q2.z * dHW;    n0 += q2.w * dWW;
        break;
    case 2:  // m = 8..11, 24..27, 40..41
        i2 += q0.x;           i0 += q0.y * dH;     i1 += q0.z * dH;     i2 += q0.w * dH;
        n0 += q1.x;           n1 += q1.y;          n2 += q1.z;          n0 += q1.w * dH;
        n1 += q2.x * dWW;     n2 += q2.y * dWW;
        break;
    default: // m = 12..15, 28..31 (q2 = tail, no coeffs)
        i0 += q0.x * dW;      i1 += q0.y * dW;     i2 += q0.z * dW;     i0 += q0.w * dHH;
        n1 += q1.x * dH;      n2 += q1.y * dH;     n0 += q1.z * dW;     n1 += q1.w * dW;
        break;
    }

    // butterfly-sum the 7 outputs within each 4-lane group
#pragma unroll
    for (int mask = 1; mask <= 2; mask <<= 1) {
        depth += __shfl_xor(depth, mask);
        i0 += __shfl_xor(i0, mask);  i1 += __shfl_xor(i1, mask);  i2 += __shfl_xor(i2, mask);
        n0 += __shfl_xor(n0, mask);  n1 += __shfl_xor(n1, mask);  n2 += __shfl_xor(n2, mask);
    }

    // heads (computed redundantly on all 4 lanes)
    depth *= vdec;
    depth = fminf(depth, -0.1f);
    i0 = fminf(fmaxf(i0 * vdec, -100.f), 100.f);
    i1 = fminf(fmaxf(i1 * vdec, -100.f), 100.f);
    i2 = fminf(fmaxf(i2 * vdec, -100.f), 100.f);
    n0 *= vdec; n1 *= vdec; n2 *= vdec;
    float ss = n0 * n0 + n1 * n1 + n2 * n2;
    float inv = rsqrtf(fmaxf(ss, 1e-12f));
    n0 *= inv; n1 *= inv; n2 *= inv;

    // distributed nontemporal store: [d,i0,i1,i2,n0,n1,n2]
    // lane g<3 writes float2 at offset 2g; lane 3 writes scalar at 6
    float* o = out + (size_t)p * 7;
    if (g < 3) {
        f32x2 v;
        v.x = (g == 0) ? depth : (g == 1) ? i1 : n0;
        v.y = (g == 0) ? i0    : (g == 1) ? i2 : n1;
        __builtin_nontemporal_store(v, (f32x2*)(o + (g << 1)));
    } else {
        __builtin_nontemporal_store(n2, o + 6);
    }
}

extern "C" void kernel_launch(void* const* d_in, const int* in_sizes, int n_in,
                              void* d_out, int out_size, void* d_ws, size_t ws_size,
                              hipStream_t stream) {
    const float* nodes = (const float*)d_in[0];
    const int*   seg   = (const int*)d_in[1];
    const int*   sp    = (const int*)d_in[2];
    float* out = (float*)d_out;

    // 262144 points x 4 lanes = 1,048,576 threads = 4096 blocks x 256
    qtr_coop_kernel<<<4096, 256, 0, stream>>>(nodes, seg, sp, out);
}